// Round 2
// baseline (2102.086 us; speedup 1.0000x reference)
//
#include <hip/hip_runtime.h>
#include <stdint.h>

#define B_  16
#define T_  12
#define N_  2048
#define DE_ 16
#define GH_ 32
#define NH_ 4

typedef __attribute__((ext_vector_type(8)))  short short8;
typedef __attribute__((ext_vector_type(4)))  float f32x4;
typedef __attribute__((ext_vector_type(16))) float f32x16;

__device__ __forceinline__ unsigned short f2b(float f){
  unsigned u = __float_as_uint(f);
  return (unsigned short)((u + 0x7fffu + ((u>>16)&1u)) >> 16);   // RNE
}
__device__ __forceinline__ float b2f(unsigned short h){
  return __uint_as_float(((unsigned)h)<<16);
}
__device__ __forceinline__ unsigned pk2(float a, float b){
  return (unsigned)f2b(a) | ((unsigned)f2b(b)<<16);
}
__device__ __forceinline__ float lrelu(float v){ return v>=0.f ? v : 0.2f*v; }

// async global->LDS, 16B per lane; lds ptr must be wave-uniform
__device__ __forceinline__ void gl16(const void* g, void* l){
  __builtin_amdgcn_global_load_lds((const __attribute__((address_space(1))) void*)g,
                                   (__attribute__((address_space(3))) void*)l, 16, 0, 0);
}

// ---------------- GAT: s,d per (head,node) ----------------
__global__ __launch_bounds__(256) void k_gat_sd(const float* __restrict__ E, const float* __restrict__ gW,
    const float* __restrict__ asrc, const float* __restrict__ adst,
    float* __restrict__ sArr, float* __restrict__ dArr)
{
  int id = blockIdx.x*256 + threadIdx.x;           // 4*2048
  int h = id >> 11, n = id & 2047;
  float hv[GH_];
#pragma unroll
  for (int f=0; f<GH_; ++f) hv[f]=0.f;
  for (int d=0; d<DE_; ++d){
    float e = E[n*DE_+d];
    const float* wr = gW + (h*DE_+d)*GH_;
#pragma unroll
    for (int f=0; f<GH_; ++f) hv[f] += e*wr[f];
  }
  float s=0.f, dd=0.f;
#pragma unroll
  for (int f=0; f<GH_; ++f){ s += hv[f]*asrc[h*GH_+f]; dd += hv[f]*adst[h*GH_+f]; }
  sArr[h*N_+n]=s; dArr[h*N_+n]=dd;
}

__global__ __launch_bounds__(256) void k_dmax(const float* __restrict__ dArr, float* __restrict__ dmax){
  __shared__ float red[256];
  int h = blockIdx.x, t = threadIdx.x;
  float m = -1e30f;
  for (int i=t;i<N_;i+=256) m = fmaxf(m, dArr[h*N_+i]);
  red[t]=m; __syncthreads();
  for (int s=128;s>0;s>>=1){ if (t<s) red[t]=fmaxf(red[t],red[t+s]); __syncthreads(); }
  if (t==0) dmax[h]=red[0];
}

__global__ __launch_bounds__(256) void k_denom(const float* __restrict__ sArr, const float* __restrict__ dArr,
                                               const float* __restrict__ dmax, float* __restrict__ denom){
  __shared__ float red[256];
  int m = blockIdx.x, h = blockIdx.y, t = threadIdx.x;
  float sm = sArr[h*N_+m];
  float shift = lrelu(sm + dmax[h]);
  float acc=0.f;
  for (int i=t;i<N_;i+=256) acc += __expf(lrelu(sm + dArr[h*N_+i]) - shift);
  red[t]=acc; __syncthreads();
  for (int s=128;s>0;s>>=1){ if (t<s) red[t]+=red[t+s]; __syncthreads(); }
  if (t==0) denom[h*N_+m]=red[0];
}

// A[m][n] bf16 row-major = mean_h softmax rows
__global__ __launch_bounds__(256) void k_adj(const float* __restrict__ sArr, const float* __restrict__ dArr,
                                             const float* __restrict__ dmax, const float* __restrict__ denom,
                                             unsigned short* __restrict__ Abf){
  int m = blockIdx.x, t = threadIdx.x;
  float sm[NH_], sh[NH_], inv[NH_];
#pragma unroll
  for (int h=0;h<NH_;++h){ sm[h]=sArr[h*N_+m]; sh[h]=lrelu(sm[h]+dmax[h]); inv[h]=1.f/denom[h*N_+m]; }
  for (int n=t;n<N_;n+=256){
    float acc=0.f;
#pragma unroll
    for (int h=0;h<NH_;++h) acc += __expf(lrelu(sm[h]+dArr[h*N_+n]) - sh[h]) * inv[h];
    Abf[(long)m*N_+n] = f2b(acc*0.25f);
  }
}

// ---------------- x transpose+convert: xsw[kb][j=bt*64+c][64] pre-swizzled bf16 ----------------
// flat(kb,j,s,e) holds x[bt][n=kb*64 + (s^(j&7))*8 + e][c=j&63]
__global__ __launch_bounds__(256) void k_xsw(const float* __restrict__ x,
                                             unsigned short* __restrict__ xsw)
{
  __shared__ unsigned short sT[256*64];
  int kb = blockIdx.x;            // 0..31
  int btB = blockIdx.y;           // 0..47
  int tid = threadIdx.x;
  int btl = tid>>6, kin = tid&63;
  int n  = kb*64 + kin;
  int bt = btB*4 + btl;
  const float* src = x + ((long)bt*N_ + n)*64;
  unsigned short row[64];
#pragma unroll
  for (int c4=0; c4<16; ++c4){
    float4 v = *(const float4*)(src + c4*4);
    row[c4*4+0]=f2b(v.x); row[c4*4+1]=f2b(v.y); row[c4*4+2]=f2b(v.z); row[c4*4+3]=f2b(v.w);
  }
  int g0 = kin>>3, e = kin&7;
#pragma unroll
  for (int c=0; c<64; ++c){
    int jl = btl*64 + c;
    int s = g0 ^ (c&7);
    sT[jl*64 + s*8 + e] = row[c];
  }
  __syncthreads();
  unsigned short* dst = xsw + ((long)kb*12288 + btB*256)*64;
  const uint4* sp = (const uint4*)sT;
  uint4* dp = (uint4*)dst;
  for (int i=tid; i<2048; i+=256) dp[i] = sp[i];
}

// ---------------- NAL weights ----------------
__global__ __launch_bounds__(256) void k_nalw(const float* __restrict__ E, const float* __restrict__ wp,
                                              unsigned short* __restrict__ Wout, int Osz){
  __shared__ float sS[256][17];
  __shared__ float sE[512*16];
  int o = blockIdx.x, q = blockIdx.y, t = threadIdx.x;
  int slot = t>>3, j = t&7;
  int kio = (((slot ^ (o&7))&31)<<3) | j;
  long dstride = 256L*Osz;
  for (int d=0; d<DE_; ++d) sS[t][d] = wp[d*dstride + (long)kio*Osz + o];
  for (int i=t; i<512*16; i+=256) sE[i] = E[q*512*16 + i];
  __syncthreads();
  unsigned short* out = Wout + (long)(q*512)*dstride + o*256 + t;
  for (int nn=0; nn<512; ++nn){
    float acc=0.f;
    const float* e = &sE[nn*16];
#pragma unroll
    for (int d=0; d<DE_; ++d) acc += e[d]*sS[t][d];
    out[(long)nn*dstride] = f2b(acc);
  }
}

__global__ __launch_bounds__(256) void k_nalb(const float* __restrict__ E, const float* __restrict__ bpg,
                                              const float* __restrict__ bpc,
                                              unsigned short* __restrict__ bg, unsigned short* __restrict__ bc){
  int id = blockIdx.x*256+threadIdx.x;
  int n = id/192, oo = id%192;
  float acc=0.f;
  if (oo<128){
    for (int d=0;d<DE_;++d) acc += E[n*DE_+d]*bpg[d*128+oo];
    bg[n*128+oo]=f2b(acc);
  } else {
    int c=oo-128;
    for (int d=0;d<DE_;++d) acc += E[n*DE_+d]*bpc[d*64+c];
    bc[n*64+c]=f2b(acc);
  }
}

__global__ __launch_bounds__(256) void k_wcat(const float* __restrict__ tcw, const float* __restrict__ rcw,
                                              unsigned short* __restrict__ Wcat){
  int id = blockIdx.x*256+threadIdx.x;
  int o = id>>8, k = id&255;
  float v;
  if (k<192){ int dt=k>>6, c=k&63; v = tcw[(o*64+c)*3+dt]; }
  else v = rcw[o*64 + (k&63)];
  int pos = o*256 + ((((k>>3)&31) ^ (o&7))<<3) + (k&7);
  Wcat[pos] = f2b(v);
}

// init: stf f32 + stb in pre-swizzled B layout
__global__ __launch_bounds__(256) void k_init2(const float* __restrict__ init, float* __restrict__ st,
                                               unsigned short* __restrict__ stb){
  int i = blockIdx.x*256+threadIdx.x;           // B*N*64
  float v = init[i]; st[i]=v;
  int c = i&63, n = (i>>6)&2047, b = i>>17;
  int kb = n>>6, kin = n&63;
  int j = b*64 + c;
  int s = (kin>>3) ^ (c&7);
  stb[((long)kb*1024 + j)*64 + s*8 + (kin&7)] = f2b(v);
}

// ---------------- unified GEMM: D[m][j] = sum_k A[m][k]*B[k][j]; B pre-swizzled ----------------
template<int BM, int BN, int JTOT>
__global__ __launch_bounds__(256) void k_gemm2(
    const unsigned short* __restrict__ A,      // [2048][2048] bf16 row-major
    const unsigned short* __restrict__ Bs,     // [32][JTOT][64] pre-swizzled
    unsigned short* __restrict__ D)            // [2048][JTOT] bf16
{
  constexpr int MBLK = 2048/BM, MPX = MBLK/8;
  constexpr int NIA = BM*64*2/(256*16);
  constexpr int NIB = BN*64*2/(256*16);
  constexpr int WTM = BM/2, WTN = BN/2;
  constexpr int MTC = WTM/32, NTC = WTN/32;
  __shared__ __align__(16) unsigned short sA[BM*64];
  __shared__ __align__(16) unsigned short sB[BN*64];
  int bid = blockIdx.x;
  int xcd = bid & 7, idx = bid >> 3;
  int mB = xcd*MPX + (idx % MPX);
  int jB = idx / MPX;
  int tid = threadIdx.x, w = tid>>6, l = tid&63;
  int wm = w&1, wn = w>>1;
  f32x16 acc[MTC][NTC];
#pragma unroll
  for (int a=0;a<MTC;++a)
#pragma unroll
    for (int b=0;b<NTC;++b)
#pragma unroll
      for (int i=0;i<16;++i) acc[a][b][i]=0.f;

  for (int kb=0; kb<32; ++kb){
    __syncthreads();
#pragma unroll
    for (int i=0;i<NIA;++i){
      int c = (w*NIA+i)*64 + l;
      int row = c>>3, slot = c&7, g = slot ^ (row&7);
      gl16((const char*)A + (((long)(mB*BM+row))*2048 + kb*64 + g*8)*2,
           (char*)sA + (w*NIA+i)*1024);
    }
    const char* bt = (const char*)(Bs + ((long)kb*JTOT + jB*BN)*64);
#pragma unroll
    for (int i=0;i<NIB;++i)
      gl16(bt + ((w*NIB+i)*64 + l)*16, (char*)sB + (w*NIB+i)*1024);
    __syncthreads();
#pragma unroll
    for (int ks=0; ks<4; ++ks){
      int gk = ks*2 + (l>>5);
      short8 af[MTC];
#pragma unroll
      for (int mt=0; mt<MTC; ++mt){
        int row = wm*WTM + mt*32 + (l&31);
        af[mt] = *(const short8*)((const char*)sA + row*128 + ((gk ^ (row&7))<<4));
      }
#pragma unroll
      for (int nt=0; nt<NTC; ++nt){
        int jj = wn*WTN + nt*32 + (l&31);
        short8 bfv = *(const short8*)((const char*)sB + jj*128 + ((gk ^ (jj&7))<<4));
#pragma unroll
        for (int mt=0; mt<MTC; ++mt)
          acc[mt][nt] = __builtin_amdgcn_mfma_f32_32x32x16_bf16(af[mt], bfv, acc[mt][nt], 0,0,0);
      }
    }
  }
#pragma unroll
  for (int mt=0; mt<MTC; ++mt)
#pragma unroll
    for (int nt=0; nt<NTC; ++nt)
#pragma unroll
      for (int rg=0; rg<16; ++rg){
        int rl = wm*WTM + mt*32 + (rg&3) + 8*(rg>>2) + 4*(l>>5);
        int col = jB*BN + wn*WTN + nt*32 + (l&31);
        long m = (long)mB*BM + rl;
        D[m*JTOT + col] = f2b(acc[mt][nt][rg]);
      }
}

// ---------------- gates ----------------
__global__ __launch_bounds__(256) void k_gates(
    const float* __restrict__ x, const float* __restrict__ st,
    const unsigned short* __restrict__ AXn, const unsigned short* __restrict__ AS,
    const unsigned short* __restrict__ Wg, const unsigned short* __restrict__ bg,
    float* __restrict__ zbuf, unsigned short* __restrict__ rsp,
    unsigned short* __restrict__ rsb, int t)
{
  __shared__ __align__(16) unsigned short sW[64*256];
  __shared__ __align__(16) unsigned short sX[16*256];
  int n = blockIdx.x, half = blockIdx.y;
  int tid = threadIdx.x, w = tid>>6, l = tid&63;
  const unsigned short* Wsrc = Wg + (long)n*32768 + half*16384;
#pragma unroll
  for (int i=0;i<8;++i){
    int c = (w*8+i)*64 + l;
    gl16((const char*)Wsrc + c*16, (char*)sW + (w*8+i)*1024);
  }
  int b = tid>>4, c16 = tid&15;
  uint4 g0, g1;
  if (c16 < 8){
    const float* p = (c16<4) ? (x  + (((long)(b*T_+t)*N_ + n)*64 + c16*16))
                             : (st + (((long)b*N_ + n)*64 + (c16-4)*16));
    float4 f0 = *(const float4*)(p+0), f1 = *(const float4*)(p+4);
    float4 f2v = *(const float4*)(p+8), f3 = *(const float4*)(p+12);
    g0.x = pk2(f0.x,f0.y); g0.y = pk2(f0.z,f0.w); g0.z = pk2(f1.x,f1.y); g0.w = pk2(f1.z,f1.w);
    g1.x = pk2(f2v.x,f2v.y); g1.y = pk2(f2v.z,f2v.w); g1.z = pk2(f3.x,f3.y); g1.w = pk2(f3.z,f3.w);
  } else {
    const unsigned short* p = (c16<12)
      ? (AXn + ((long)n*12288 + (b*T_+t)*64 + (c16-8)*16))
      : (AS  + ((long)n*1024  + b*64       + (c16-12)*16));
    g0 = *(const uint4*)(p); g1 = *(const uint4*)(p+8);
  }
  {
    int gg = c16*2;
    *(uint4*)((char*)sX + b*512 + (((gg  ) ^ (b&7))<<4)) = g0;
    *(uint4*)((char*)sX + b*512 + (((gg+1) ^ (b&7))<<4)) = g1;
  }
  __syncthreads();
  f32x4 acc;
#pragma unroll
  for (int i=0;i<4;++i) acc[i]=0.f;
  int orow = w*16 + (l&15);
  int arow = l&15;
#pragma unroll
  for (int ks=0; ks<8; ++ks){
    int g = ks*4 + (l>>4);
    short8 a = *(const short8*)((const char*)sX + arow*512 + ((g ^ (arow&7))<<4));
    short8 bb = *(const short8*)((const char*)sW + orow*512 + ((g ^ (orow&7))<<4));
    acc = __builtin_amdgcn_mfma_f32_16x16x32_bf16(a, bb, acc, 0,0,0);
  }
  int o = half*64 + orow;
  float bia = b2f(bg[n*128 + o]);
  int kb = n>>6, kin = n&63;
  int sw = (kin>>3) ^ (orow&7);
#pragma unroll
  for (int i=0;i<4;++i){
    int b2 = (l>>4)*4 + i;
    float v = acc[i] + bia;
    float sg = 1.f/(1.f+__expf(-v));
    long idx = ((long)b2*N_ + n)*64;
    if (half==0) zbuf[idx + o] = sg;
    else {
      float s0v = st[idx + orow];
      unsigned short rv = f2b(sg*s0v);
      rsp[idx + orow] = rv;
      rsb[((long)kb*1024 + b2*64 + orow)*64 + sw*8 + (kin&7)] = rv;
    }
  }
}

// ---------------- candidate + state update ----------------
__global__ __launch_bounds__(256) void k_cand(
    const float* __restrict__ x, const float* __restrict__ zbuf,
    const unsigned short* __restrict__ AXn, const unsigned short* __restrict__ ARS,
    const unsigned short* __restrict__ rsp,
    const unsigned short* __restrict__ Wc, const unsigned short* __restrict__ bc,
    float* __restrict__ st, unsigned short* __restrict__ stb,
    unsigned short* __restrict__ inner, int t)
{
  __shared__ __align__(16) unsigned short sW[64*256];
  __shared__ __align__(16) unsigned short sX[16*256];
  int n = blockIdx.x;
  int tid = threadIdx.x, w = tid>>6, l = tid&63;
  const unsigned short* Wsrc = Wc + (long)n*16384;
#pragma unroll
  for (int i=0;i<8;++i){
    int c = (w*8+i)*64 + l;
    gl16((const char*)Wsrc + c*16, (char*)sW + (w*8+i)*1024);
  }
  int b = tid>>4, c16 = tid&15;
  uint4 g0, g1;
  if (c16 < 4){
    const float* p = x + (((long)(b*T_+t)*N_ + n)*64 + c16*16);
    float4 f0 = *(const float4*)(p+0), f1 = *(const float4*)(p+4);
    float4 f2v = *(const float4*)(p+8), f3 = *(const float4*)(p+12);
    g0.x = pk2(f0.x,f0.y); g0.y = pk2(f0.z,f0.w); g0.z = pk2(f1.x,f1.y); g0.w = pk2(f1.z,f1.w);
    g1.x = pk2(f2v.x,f2v.y); g1.y = pk2(f2v.z,f2v.w); g1.z = pk2(f3.x,f3.y); g1.w = pk2(f3.z,f3.w);
  } else {
    const unsigned short* p;
    if (c16<8)       p = rsp + (((long)b*N_ + n)*64 + (c16-4)*16);
    else if (c16<12) p = AXn + ((long)n*12288 + (b*T_+t)*64 + (c16-8)*16);
    else             p = ARS + ((long)n*1024  + b*64       + (c16-12)*16);
    g0 = *(const uint4*)(p); g1 = *(const uint4*)(p+8);
  }
  {
    int gg = c16*2;
    *(uint4*)((char*)sX + b*512 + (((gg  ) ^ (b&7))<<4)) = g0;
    *(uint4*)((char*)sX + b*512 + (((gg+1) ^ (b&7))<<4)) = g1;
  }
  __syncthreads();
  f32x4 acc;
#pragma unroll
  for (int i=0;i<4;++i) acc[i]=0.f;
  int orow = w*16 + (l&15);
  int arow = l&15;
#pragma unroll
  for (int ks=0; ks<8; ++ks){
    int g = ks*4 + (l>>4);
    short8 a = *(const short8*)((const char*)sX + arow*512 + ((g ^ (arow&7))<<4));
    short8 bb = *(const short8*)((const char*)sW + orow*512 + ((g ^ (orow&7))<<4));
    acc = __builtin_amdgcn_mfma_f32_16x16x32_bf16(a, bb, acc, 0,0,0);
  }
  float bia = b2f(bc[n*64 + orow]);
  int kb = n>>6, kin = n&63;
  int sw = (kin>>3) ^ (orow&7);
#pragma unroll
  for (int i=0;i<4;++i){
    int b2 = (l>>4)*4 + i;
    float hc = tanhf(acc[i] + bia);
    long idx = ((long)b2*N_ + n)*64 + orow;
    float zv = zbuf[idx];
    float olds = st[idx];
    float nv = zv*olds + (1.f-zv)*hc;
    st[idx]=nv;
    unsigned short nb = f2b(nv);
    stb[((long)kb*1024 + b2*64 + orow)*64 + sw*8 + (kin&7)] = nb;
    inner[((long)(b2*T_+t)*N_ + n)*64 + orow] = nb;
  }
}

// ---------------- post: temporal conv + residual + relu + layernorm ----------------
__global__ __launch_bounds__(256) void k_post(
    const unsigned short* __restrict__ inner, const float* __restrict__ x,
    const unsigned short* __restrict__ Wcat,
    const float* __restrict__ tcb, const float* __restrict__ rcb,
    const float* __restrict__ lng, const float* __restrict__ lnb,
    float* __restrict__ out)
{
  __shared__ __align__(16) unsigned short sF[64*256];
  __shared__ __align__(16) unsigned short sW[64*256];
  int id = blockIdx.x;
  int bt = id>>5, nb = id&31;
  int b = bt/T_, t = bt%T_;
  int n0 = nb*64;
  int tid = threadIdx.x, w = tid>>6, l = tid&63;
#pragma unroll
  for (int i=0;i<8;++i){
    int c = (w*8+i)*64 + l;
    gl16((const char*)Wcat + c*16, (char*)sW + (w*8+i)*1024);
  }
  int row = tid&63, q = tid>>6;
  uint4 ch[8];
  if (q<3){
    int ts = t + q - 1;
    if (ts>=0 && ts<T_){
      const uint4* p = (const uint4*)(inner + (((long)(b*T_+ts)*N_) + n0+row)*64);
#pragma unroll
      for (int hh=0;hh<8;++hh) ch[hh]=p[hh];
    } else {
      uint4 zz; zz.x=0u; zz.y=0u; zz.z=0u; zz.w=0u;
#pragma unroll
      for (int hh=0;hh<8;++hh) ch[hh]=zz;
    }
  } else {
    const float4* p = (const float4*)(x + (((long)bt*N_) + n0+row)*64);
#pragma unroll
    for (int hh=0;hh<8;++hh){
      float4 u0=p[2*hh], u1=p[2*hh+1];
      ch[hh].x=pk2(u0.x,u0.y); ch[hh].y=pk2(u0.z,u0.w);
      ch[hh].z=pk2(u1.x,u1.y); ch[hh].w=pk2(u1.z,u1.w);
    }
  }
#pragma unroll
  for (int hh=0;hh<8;++hh){
    int g = q*8+hh;
    *(uint4*)((char*)sF + row*512 + ((g ^ (row&7))<<4)) = ch[hh];
  }
  __syncthreads();
  f32x4 acc[4];
#pragma unroll
  for (int ot=0; ot<4; ++ot)
#pragma unroll
    for (int i=0;i<4;++i) acc[ot][i]=0.f;
  int arow = w*16 + (l&15);
#pragma unroll
  for (int ks=0; ks<8; ++ks){
    int g = ks*4 + (l>>4);
    short8 a = *(const short8*)((const char*)sF + arow*512 + ((g ^ (arow&7))<<4));
#pragma unroll
    for (int ot=0; ot<4; ++ot){
      int o = ot*16 + (l&15);
      short8 bb = *(const short8*)((const char*)sW + o*512 + ((g ^ (o&7))<<4));
      acc[ot] = __builtin_amdgcn_mfma_f32_16x16x32_bf16(a, bb, acc[ot], 0,0,0);
    }
  }
  float s1[4]={0.f,0.f,0.f,0.f}, s2[4]={0.f,0.f,0.f,0.f};
#pragma unroll
  for (int ot=0; ot<4; ++ot){
    int o = ot*16 + (l&15);
    float bia = tcb[o] + rcb[o];
#pragma unroll
    for (int i=0;i<4;++i){
      float v = fmaxf(acc[ot][i] + bia, 0.f);
      acc[ot][i] = v;
      s1[i]+=v; s2[i]+=v*v;
    }
  }
#pragma unroll
  for (int msk=1; msk<16; msk<<=1){
#pragma unroll
    for (int i=0;i<4;++i){
      s1[i] += __shfl_xor(s1[i], msk, 64);
      s2[i] += __shfl_xor(s2[i], msk, 64);
    }
  }
#pragma unroll
  for (int i=0;i<4;++i){
    float mu = s1[i]*(1.f/64.f);
    float var = s2[i]*(1.f/64.f) - mu*mu;
    float rstd = rsqrtf(fmaxf(var,0.f)+1e-5f);
    int rr = n0 + w*16 + (l>>4)*4 + i;
#pragma unroll
    for (int ot=0; ot<4; ++ot){
      int o = ot*16 + (l&15);
      out[(((long)bt*N_) + rr)*64 + o] = (acc[ot][i]-mu)*rstd*lng[o] + lnb[o];
    }
  }
}

// ---------------- launch ----------------
extern "C" void kernel_launch(void* const* d_in, const int* in_sizes, int n_in,
                              void* d_out, int out_size, void* d_ws, size_t ws_size,
                              hipStream_t stream)
{
  const float* x    = (const float*)d_in[0];
  const float* init = (const float*)d_in[1];
  const float* E    = (const float*)d_in[2];
  const float* gW   = (const float*)d_in[3];
  const float* asrc = (const float*)d_in[4];
  const float* adst = (const float*)d_in[5];
  const float* wpg  = (const float*)d_in[6];
  const float* bpg  = (const float*)d_in[7];
  const float* wpc  = (const float*)d_in[8];
  const float* bpc  = (const float*)d_in[9];
  const float* tcw  = (const float*)d_in[10];
  const float* tcb  = (const float*)d_in[11];
  const float* rcw  = (const float*)d_in[12];
  const float* rcb  = (const float*)d_in[13];
  const float* lng  = (const float*)d_in[14];
  const float* lnb  = (const float*)d_in[15];
  float* out = (float*)d_out;

  char* p = (char*)d_ws;
  auto alloc = [&](size_t bytes)->char*{ char* r = p; p += (bytes + 255) & ~(size_t)255; return r; };
  unsigned short* Abf  = (unsigned short*)alloc((size_t)N_*N_*2);
  unsigned short* Wg   = (unsigned short*)alloc((size_t)N_*32768*2);
  unsigned short* Wc   = (unsigned short*)alloc((size_t)N_*16384*2);
  unsigned short* bg   = (unsigned short*)alloc((size_t)N_*128*2);
  unsigned short* bc   = (unsigned short*)alloc((size_t)N_*64*2);
  unsigned short* xsw  = (unsigned short*)alloc((size_t)N_*12288*2);
  unsigned short* AXn  = (unsigned short*)alloc((size_t)N_*12288*2);
  unsigned short* AS   = (unsigned short*)alloc((size_t)N_*1024*2);
  unsigned short* ARS  = (unsigned short*)alloc((size_t)N_*1024*2);
  unsigned short* rsb  = (unsigned short*)alloc((size_t)N_*1024*2);
  unsigned short* rsp  = (unsigned short*)alloc((size_t)N_*1024*2);
  unsigned short* stb  = (unsigned short*)alloc((size_t)N_*1024*2);
  unsigned short* inner= (unsigned short*)alloc((size_t)B_*T_*N_*64*2);
  unsigned short* Wcat = (unsigned short*)alloc((size_t)64*256*2);
  float* sArr = (float*)alloc((size_t)NH_*N_*4);
  float* dArr = (float*)alloc((size_t)NH_*N_*4);
  float* dmax = (float*)alloc((size_t)NH_*4);
  float* denom= (float*)alloc((size_t)NH_*N_*4);
  float* stf  = (float*)alloc((size_t)B_*N_*64*4);
  float* zbuf = (float*)alloc((size_t)B_*N_*64*4);

  k_gat_sd<<<32,256,0,stream>>>(E,gW,asrc,adst,sArr,dArr);
  k_dmax<<<4,256,0,stream>>>(dArr,dmax);
  k_denom<<<dim3(N_,NH_),256,0,stream>>>(sArr,dArr,dmax,denom);
  k_adj<<<N_,256,0,stream>>>(sArr,dArr,dmax,denom,Abf);
  k_xsw<<<dim3(32,48),256,0,stream>>>(x,xsw);
  k_nalw<<<dim3(128,4),256,0,stream>>>(E,wpg,Wg,128);
  k_nalw<<<dim3(64,4),256,0,stream>>>(E,wpc,Wc,64);
  k_nalb<<<1536,256,0,stream>>>(E,bpg,bpc,bg,bc);
  k_wcat<<<64,256,0,stream>>>(tcw,rcw,Wcat);
  k_init2<<<(B_*N_*64)/256,256,0,stream>>>(init,stf,stb);

  // AXn[m][j=(b*T+t)*64+c] = (A @ x[b][t])[m][c]  as one 2048x12288x2048 GEMM
  k_gemm2<128,128,12288><<<1536,256,0,stream>>>(Abf, xsw, AXn);

  for (int t=0; t<T_; ++t){
    k_gemm2<64,64,1024><<<512,256,0,stream>>>(Abf, stb, AS);
    k_gates<<<dim3(N_,2),256,0,stream>>>(x,stf,AXn,AS,Wg,bg,zbuf,rsp,rsb,t);
    k_gemm2<64,64,1024><<<512,256,0,stream>>>(Abf, rsb, ARS);
    k_cand<<<N_,256,0,stream>>>(x,zbuf,AXn,ARS,rsp,Wc,bc,stf,stb,inner,t);
  }

  k_post<<<B_*T_*32,256,0,stream>>>(inner,x,Wcat,tcb,rcb,lng,lnb,out);
  hipMemcpyAsync(out + (size_t)B_*T_*N_*64, stf, (size_t)B_*N_*64*4,
                 hipMemcpyDeviceToDevice, stream);
}